// Round 2
// baseline (809.654 us; speedup 1.0000x reference)
//
#include <hip/hip_runtime.h>
#include <math.h>

typedef _Float16 half8  __attribute__((ext_vector_type(8)));
typedef _Float16 half4  __attribute__((ext_vector_type(4)));
typedef __fp16   f16x2  __attribute__((ext_vector_type(2)));
typedef float    floatx4 __attribute__((ext_vector_type(4)));

#define B_   2
#define L_   8192
#define H_   16
#define D_   64
#define C_   1024
#define NC_  8
#define HD_  1024             // global row stride in floats
#define KSTR 72               // Kl row stride (f16)
#define VSTR 40               // Vt row stride (f16)
#define LOG2B 0.41524101186098314f   // log2(10000)/32
#define LOG2E 1.4426950408889634f
#define DTHR  8.0f            // defer-rescale threshold (log2 units): P <= 2^8, safe in f16

__device__ __forceinline__ float fast_exp2(float x) {
#if __has_builtin(__builtin_amdgcn_exp2f)
    return __builtin_amdgcn_exp2f(x);
#else
    return exp2f(x);
#endif
}

__device__ __forceinline__ unsigned pk16(float a, float b) {
    f16x2 r = __builtin_amdgcn_cvt_pkrtz(a, b);   // v_cvt_pkrtz_f16_f32
    return __builtin_bit_cast(unsigned, r);
}

__device__ __forceinline__ float rormax16(float v) {
    int x;
    x = __builtin_amdgcn_mov_dpp(__float_as_int(v), 0x121, 0xf, 0xf, true); v = fmaxf(v, __int_as_float(x));
    x = __builtin_amdgcn_mov_dpp(__float_as_int(v), 0x122, 0xf, 0xf, true); v = fmaxf(v, __int_as_float(x));
    x = __builtin_amdgcn_mov_dpp(__float_as_int(v), 0x124, 0xf, 0xf, true); v = fmaxf(v, __int_as_float(x));
    x = __builtin_amdgcn_mov_dpp(__float_as_int(v), 0x128, 0xf, 0xf, true); v = fmaxf(v, __int_as_float(x));
    return v;
}

__global__ __launch_bounds__(256, 4)
void attn_v4(const float* __restrict__ qg, const float* __restrict__ kg,
             const float* __restrict__ vg, const int* __restrict__ sidx,
             float* __restrict__ outg)
{
    __shared__ __align__(16) _Float16 Kl[32 * KSTR];     // K tile, RoPE'd, f16 [k][d]
    __shared__ __align__(16) _Float16 Vt[64 * VSTR];     // V tile, f16, transposed [dv][k]
    __shared__ __align__(16) _Float16 Pt[4][32 * 16];    // per-wave P^T slab [k][q], stride 16

    const int t  = threadIdx.x;
    const int w  = t >> 6;         // wave 0..3
    const int lg = (t >> 4) & 3;   // 16-lane group
    const int ln = t & 15;

    const int bid = blockIdx.x;
    // j in the SLOWEST bits: round-robin dispatch gives CU c blocks {c, c+256, c+512, c+768}
    // = the four j-variants of ONE (b,n,h): per-CU work balanced (j-work spans 1.4x) and
    // K/V shared through L1/L2 instead of refetched.
    const int j   = bid >> 8;
    const int grp = bid & 255;
    const int h   = grp & 15;
    const int n   = (grp >> 4) & 7;
    const int b   = grp >> 7;

    const int p0   = sidx[0] + n * C_;       // absolute position of chunk row 0
    const int qoff = j * 64 + w * 16;        // wave's strip offset; strip s at qoff + s*256

    const long bhbase = ((long)b * L_ + (long)n * C_) * HD_ + (long)h * D_;
    const float* kbase = kg + bhbase;
    const float* vbase = vg + bhbase;

    // ---- Q fragments (A-layout) per strip, RoPE'd, f16, pre-scaled by log2(e) ----
    half8 aq[4][2];
    const int d0 = lg * 8;
    #pragma unroll
    for (int s = 0; s < 4; ++s) {
        const int qr = s * 256 + qoff + ln;
        const float* qp = qg + bhbase + (long)qr * HD_;
        float4 f0 = *(const float4*)(qp + d0);
        float4 f1 = *(const float4*)(qp + d0 + 4);
        float4 g0 = *(const float4*)(qp + d0 + 32);
        float4 g1 = *(const float4*)(qp + d0 + 36);
        float x[8] = {f0.x,f0.y,f0.z,f0.w,f1.x,f1.y,f1.z,f1.w};
        float y[8] = {g0.x,g0.y,g0.z,g0.w,g1.x,g1.y,g1.z,g1.w};
        const float pos = (float)(p0 + qr);
        #pragma unroll
        for (int jj = 0; jj < 8; ++jj) {
            float invf = fast_exp2(-(float)(d0 + jj) * LOG2B);
            float sn, cs; __sincosf(pos * invf, &sn, &cs);
            aq[s][0][jj] = (_Float16)((x[jj] * cs - y[jj] * sn) * LOG2E);
            aq[s][1][jj] = (_Float16)((y[jj] * cs + x[jj] * sn) * LOG2E);
        }
    }

    // ---- accumulators ----
    floatx4 O[4][4];     // [strip][dvt]; C-layout row = lg*4+reg, col = dvt*16+ln
    floatx4 Ol[4];       // row-sum via ones-MFMA
    float   mr[4][4];    // running max (log2 domain)
    #pragma unroll
    for (int s = 0; s < 4; ++s) {
        Ol[s] = (floatx4){0.f,0.f,0.f,0.f};
        #pragma unroll
        for (int dt = 0; dt < 4; ++dt) O[s][dt] = (floatx4){0.f,0.f,0.f,0.f};
        #pragma unroll
        for (int r = 0; r < 4; ++r) mr[s][r] = -1e30f;
    }
    half8 bones;
    #pragma unroll
    for (int jj = 0; jj < 8; ++jj) bones[jj] = (_Float16)1.0f;

    // ---- staging decomposition ----
    const int sr = t >> 3;           // K: row 0..31
    const int sc = (t & 7) * 4;      // K: col quad
    float sinvk[4];
    #pragma unroll
    for (int i = 0; i < 4; ++i) sinvk[i] = fast_exp2(-(float)(sc + i) * LOG2B);
    const int vc = t & 31;           // V: dv-pair index (dv = 2vc, 2vc+1)
    const int vr = (t >> 5) * 4;     // V: k-row base 0..28

    const int NKT = ((831 + j * 64) >> 5) + 1;   // block staging tiles (26..32)
    int nkt_s[4];
    #pragma unroll
    for (int s = 0; s < 4; ++s) nkt_s[s] = ((s * 256 + qoff + 15) >> 5) + 1;

    // per-lane address for the hardware transpose-read of P^T
    const unsigned trad = (unsigned)(unsigned long long)(uintptr_t)(&Pt[w][0])
                        + 8u * (unsigned)ln + 256u * (unsigned)lg;

    // ---- prefetch tile 0 into registers ----
    float4 kp0, kp1; float2 vp0, vp1, vp2, vp3;
    {
        const float* kp = kbase + (long)sr * HD_ + sc;
        kp0 = *(const float4*)kp; kp1 = *(const float4*)(kp + 32);
        const float* vp = vbase + (long)vr * HD_ + 2 * vc;
        vp0 = *(const float2*)vp;           vp1 = *(const float2*)(vp + HD_);
        vp2 = *(const float2*)(vp + 2*HD_); vp3 = *(const float2*)(vp + 3*HD_);
    }

    for (int kt = 0; kt < NKT; ++kt) {
        const int kb0 = kt * 32;
        __syncthreads();   // previous tile fully consumed
        {   // ---- write staged tile: RoPE K, repack V (b64 writes) ----
            const float pos = (float)(p0 + kb0 + sr);
            float ka[4] = {kp0.x,kp0.y,kp0.z,kp0.w};
            float kc[4] = {kp1.x,kp1.y,kp1.z,kp1.w};
            half4 o0, o1;
            #pragma unroll
            for (int i = 0; i < 4; ++i) {
                float sn, cs; __sincosf(pos * sinvk[i], &sn, &cs);
                o0[i] = (_Float16)(ka[i] * cs - kc[i] * sn);
                o1[i] = (_Float16)(kc[i] * cs + ka[i] * sn);
            }
            *(half4*)(&Kl[sr * KSTR + sc])      = o0;
            *(half4*)(&Kl[sr * KSTR + sc + 32]) = o1;
            half4 va, vb;
            va[0] = (_Float16)vp0.x; va[1] = (_Float16)vp1.x; va[2] = (_Float16)vp2.x; va[3] = (_Float16)vp3.x;
            vb[0] = (_Float16)vp0.y; vb[1] = (_Float16)vp1.y; vb[2] = (_Float16)vp2.y; vb[3] = (_Float16)vp3.y;
            *(half4*)(&Vt[(2 * vc)     * VSTR + vr]) = va;
            *(half4*)(&Vt[(2 * vc + 1) * VSTR + vr]) = vb;
        }
        if (kt + 1 < NKT) {   // ---- prefetch next tile (lands during compute) ----
            const int kb1 = kb0 + 32;
            const float* kp = kbase + (long)(kb1 + sr) * HD_ + sc;
            kp0 = *(const float4*)kp; kp1 = *(const float4*)(kp + 32);
            const float* vp = vbase + (long)(kb1 + vr) * HD_ + 2 * vc;
            vp0 = *(const float2*)vp;           vp1 = *(const float2*)(vp + HD_);
            vp2 = *(const float2*)(vp + 2*HD_); vp3 = *(const float2*)(vp + 3*HD_);
        }
        __syncthreads();   // tile visible

        // ---- fragments shared across strips ----
        half8 bk0[2], bk1[2], bv[4];
        #pragma unroll
        for (int ct = 0; ct < 2; ++ct) {
            const _Float16* kr = &Kl[(ct * 16 + ln) * KSTR + lg * 8];
            bk0[ct] = *(const half8*)kr;
            bk1[ct] = *(const half8*)(kr + 32);
        }
        #pragma unroll
        for (int dt = 0; dt < 4; ++dt)
            bv[dt] = *(const half8*)(&Vt[(dt * 16 + ln) * VSTR + lg * 8]);

        #pragma unroll
        for (int s = 0; s < 4; ++s) {
            if (kt >= nkt_s[s]) continue;          // wave-uniform
            const int qs = s * 256 + qoff;

            floatx4 sacc[2];
            #pragma unroll
            for (int ct = 0; ct < 2; ++ct) {
                floatx4 acc = (floatx4){0.f,0.f,0.f,0.f};
                acc = __builtin_amdgcn_mfma_f32_16x16x32_f16(aq[s][0], bk0[ct], acc, 0, 0, 0);
                acc = __builtin_amdgcn_mfma_f32_16x16x32_f16(aq[s][1], bk1[ct], acc, 0, 0, 0);
                sacc[ct] = acc;
            }
            if (kb0 + 31 > qs) {                   // diagonal tile: mask
                #pragma unroll
                for (int ct = 0; ct < 2; ++ct) {
                    const int kkc = kb0 + ct * 16 + ln;
                    #pragma unroll
                    for (int r = 0; r < 4; ++r)
                        if (kkc > qs + lg * 4 + r) sacc[ct][r] = -1e30f;
                }
            }

            // ---- deferred-max online softmax (log2 domain) ----
            float tm[4];
            int grow = 0;
            #pragma unroll
            for (int r = 0; r < 4; ++r) {
                tm[r] = rormax16(fmaxf(sacc[0][r], sacc[1][r]));
                grow |= (tm[r] > mr[s][r] + DTHR) ? 1 : 0;
            }
            if (__any(grow)) {                     // rare after the first tile of a strip
                #pragma unroll
                for (int r = 0; r < 4; ++r) {
                    float mnew  = fmaxf(mr[s][r], tm[r]);
                    float alpha = fast_exp2(mr[s][r] - mnew);
                    mr[s][r] = mnew;
                    Ol[s][r] *= alpha;
                    #pragma unroll
                    for (int dt = 0; dt < 4; ++dt) O[s][dt][r] *= alpha;
                }
            }

            // ---- P packed to f16 pairs, stored TRANSPOSED [k][q]: two b64 conflict-free writes ----
            uint2 wa, wb;
            wa.x = pk16(fast_exp2(sacc[0][0] - mr[s][0]), fast_exp2(sacc[0][1] - mr[s][1]));
            wa.y = pk16(fast_exp2(sacc[0][2] - mr[s][2]), fast_exp2(sacc[0][3] - mr[s][3]));
            wb.x = pk16(fast_exp2(sacc[1][0] - mr[s][0]), fast_exp2(sacc[1][1] - mr[s][1]));
            wb.y = pk16(fast_exp2(sacc[1][2] - mr[s][2]), fast_exp2(sacc[1][3] - mr[s][3]));
            *(uint2*)(&Pt[w][ ln       * 16 + lg * 4]) = wa;
            *(uint2*)(&Pt[w][(16 + ln) * 16 + lg * 4]) = wb;
            asm volatile("s_waitcnt lgkmcnt(0)" ::: "memory");
            // hardware transpose-read recovers the A-fragment: ap[j] = P[q=ln][k=8*lg+j]
            half4 tlo, thi;
            asm volatile("ds_read_b64_tr_b16 %0, %2\n\t"
                         "ds_read_b64_tr_b16 %1, %2 offset:128"
                         : "=&v"(tlo), "=&v"(thi) : "v"(trad));
            asm volatile("s_waitcnt lgkmcnt(0)" ::: "memory");
            __builtin_amdgcn_sched_barrier(0);
            half8 ap = __builtin_shufflevector(tlo, thi, 0, 1, 2, 3, 4, 5, 6, 7);

            #pragma unroll
            for (int dt = 0; dt < 4; ++dt)
                O[s][dt] = __builtin_amdgcn_mfma_f32_16x16x32_f16(ap, bv[dt], O[s][dt], 0, 0, 0);
            Ol[s] = __builtin_amdgcn_mfma_f32_16x16x32_f16(ap, bones, Ol[s], 0, 0, 0);
        }
    }

    // ---- epilogue ----
    #pragma unroll
    for (int s = 0; s < 4; ++s) {
        const int qs = s * 256 + qoff;
        float inv[4];
        #pragma unroll
        for (int r = 0; r < 4; ++r) inv[r] = 1.0f / Ol[s][r];
        #pragma unroll
        for (int dt = 0; dt < 4; ++dt) {
            #pragma unroll
            for (int r = 0; r < 4; ++r) {
                const int qr = qs + lg * 4 + r;
                outg[bhbase + (long)qr * HD_ + dt * 16 + ln] = O[s][dt][r] * inv[r];
            }
        }
    }
}

extern "C" void kernel_launch(void* const* d_in, const int* in_sizes, int n_in,
                              void* d_out, int out_size, void* d_ws, size_t ws_size,
                              hipStream_t stream) {
    const float* q    = (const float*)d_in[0];
    const float* k    = (const float*)d_in[1];
    const float* v    = (const float*)d_in[2];
    const int*   sidx = (const int*)d_in[3];
    float*       out  = (float*)d_out;

    dim3 grid(B_ * NC_ * H_ * 4);   // 1024 blocks: (j slow | b, n, h fast)
    dim3 block(256);
    attn_v4<<<grid, block, 0, stream>>>(q, k, v, sidx, out);
}

// Round 3
// 282.856 us; speedup vs baseline: 2.8624x; 2.8624x over previous
//
#include <hip/hip_runtime.h>
#include <math.h>

typedef _Float16 half8  __attribute__((ext_vector_type(8)));
typedef _Float16 half4  __attribute__((ext_vector_type(4)));
typedef __fp16   f16x2  __attribute__((ext_vector_type(2)));
typedef float    floatx4 __attribute__((ext_vector_type(4)));

#define B_   2
#define L_   8192
#define H_   16
#define D_   64
#define C_   1024
#define NC_  8
#define HD_  1024             // global row stride in floats
#define KSTR 72               // Kl row stride (f16)
#define VSTR 40               // Vt row stride (f16)
#define LOG2B 0.41524101186098314f   // log2(10000)/32
#define LOG2E 1.4426950408889634f
#define DTHR  8.0f            // defer-rescale threshold (log2 units): P <= 2^8, safe in f16

__device__ __forceinline__ float fast_exp2(float x) {
#if __has_builtin(__builtin_amdgcn_exp2f)
    return __builtin_amdgcn_exp2f(x);
#else
    return exp2f(x);
#endif
}

__device__ __forceinline__ unsigned pk16(float a, float b) {
    f16x2 r = __builtin_amdgcn_cvt_pkrtz(a, b);   // v_cvt_pkrtz_f16_f32
    return __builtin_bit_cast(unsigned, r);
}

__device__ __forceinline__ float rormax16(float v) {
    int x;
    x = __builtin_amdgcn_mov_dpp(__float_as_int(v), 0x121, 0xf, 0xf, true); v = fmaxf(v, __int_as_float(x));
    x = __builtin_amdgcn_mov_dpp(__float_as_int(v), 0x122, 0xf, 0xf, true); v = fmaxf(v, __int_as_float(x));
    x = __builtin_amdgcn_mov_dpp(__float_as_int(v), 0x124, 0xf, 0xf, true); v = fmaxf(v, __int_as_float(x));
    x = __builtin_amdgcn_mov_dpp(__float_as_int(v), 0x128, 0xf, 0xf, true); v = fmaxf(v, __int_as_float(x));
    return v;
}

// NOTE: min-waves hint MUST stay at 2. This kernel's live state (O[4][4] f32
// accumulators + Q fragments + prefetch regs) needs ~120 VGPRs; (256,4) forced
// a 64-VGPR budget and spilled the accumulators in the K-loop:
// WRITE_SIZE 65MB -> 1.24GB, dur 165us -> 682us (Round 2 post-mortem).
__global__ __launch_bounds__(256, 2)
void attn_v5(const float* __restrict__ qg, const float* __restrict__ kg,
             const float* __restrict__ vg, const int* __restrict__ sidx,
             float* __restrict__ outg)
{
    __shared__ __align__(16) _Float16 Kl[32 * KSTR];     // K tile, RoPE'd, f16 [k][d]
    __shared__ __align__(16) _Float16 Vt[64 * VSTR];     // V tile, f16, transposed [dv][k]
    __shared__ __align__(16) _Float16 Pt[4][32 * 16];    // per-wave P^T slab [k][q], stride 16

    const int t  = threadIdx.x;
    const int w  = t >> 6;         // wave 0..3
    const int lg = (t >> 4) & 3;   // 16-lane group
    const int ln = t & 15;

    const int bid = blockIdx.x;
    // j in the SLOWEST bits: round-robin dispatch gives CU c blocks {c, c+256, c+512, c+768}
    // = the four j-variants of ONE (b,n,h): per-CU work balanced (j-work spans 1.4x) and
    // K/V shared through L1/L2 instead of refetched.
    const int j   = bid >> 8;
    const int grp = bid & 255;
    const int h   = grp & 15;
    const int n   = (grp >> 4) & 7;
    const int b   = grp >> 7;

    const int p0   = sidx[0] + n * C_;       // absolute position of chunk row 0
    const int qoff = j * 64 + w * 16;        // wave's strip offset; strip s at qoff + s*256

    const long bhbase = ((long)b * L_ + (long)n * C_) * HD_ + (long)h * D_;
    const float* kbase = kg + bhbase;
    const float* vbase = vg + bhbase;

    // ---- Q fragments (A-layout) per strip, RoPE'd, f16, pre-scaled by log2(e) ----
    half8 aq[4][2];
    const int d0 = lg * 8;
    #pragma unroll
    for (int s = 0; s < 4; ++s) {
        const int qr = s * 256 + qoff + ln;
        const float* qp = qg + bhbase + (long)qr * HD_;
        float4 f0 = *(const float4*)(qp + d0);
        float4 f1 = *(const float4*)(qp + d0 + 4);
        float4 g0 = *(const float4*)(qp + d0 + 32);
        float4 g1 = *(const float4*)(qp + d0 + 36);
        float x[8] = {f0.x,f0.y,f0.z,f0.w,f1.x,f1.y,f1.z,f1.w};
        float y[8] = {g0.x,g0.y,g0.z,g0.w,g1.x,g1.y,g1.z,g1.w};
        const float pos = (float)(p0 + qr);
        #pragma unroll
        for (int jj = 0; jj < 8; ++jj) {
            float invf = fast_exp2(-(float)(d0 + jj) * LOG2B);
            float sn, cs; __sincosf(pos * invf, &sn, &cs);
            aq[s][0][jj] = (_Float16)((x[jj] * cs - y[jj] * sn) * LOG2E);
            aq[s][1][jj] = (_Float16)((y[jj] * cs + x[jj] * sn) * LOG2E);
        }
    }

    // ---- accumulators ----
    floatx4 O[4][4];     // [strip][dvt]; C-layout row = lg*4+reg, col = dvt*16+ln
    floatx4 Ol[4];       // row-sum via ones-MFMA
    float   mr[4][4];    // running max (log2 domain)
    #pragma unroll
    for (int s = 0; s < 4; ++s) {
        Ol[s] = (floatx4){0.f,0.f,0.f,0.f};
        #pragma unroll
        for (int dt = 0; dt < 4; ++dt) O[s][dt] = (floatx4){0.f,0.f,0.f,0.f};
        #pragma unroll
        for (int r = 0; r < 4; ++r) mr[s][r] = -1e30f;
    }
    half8 bones;
    #pragma unroll
    for (int jj = 0; jj < 8; ++jj) bones[jj] = (_Float16)1.0f;

    // ---- staging decomposition ----
    const int sr = t >> 3;           // K: row 0..31
    const int sc = (t & 7) * 4;      // K: col quad
    float sinvk[4];
    #pragma unroll
    for (int i = 0; i < 4; ++i) sinvk[i] = fast_exp2(-(float)(sc + i) * LOG2B);
    const int vc = t & 31;           // V: dv-pair index (dv = 2vc, 2vc+1)
    const int vr = (t >> 5) * 4;     // V: k-row base 0..28

    const int NKT = ((831 + j * 64) >> 5) + 1;   // block staging tiles (26..32)
    int nkt_s[4];
    #pragma unroll
    for (int s = 0; s < 4; ++s) nkt_s[s] = ((s * 256 + qoff + 15) >> 5) + 1;

    // per-lane address for the hardware transpose-read of P^T
    const unsigned trad = (unsigned)(unsigned long long)(uintptr_t)(&Pt[w][0])
                        + 8u * (unsigned)ln + 256u * (unsigned)lg;

    // ---- prefetch tile 0 into registers ----
    float4 kp0, kp1; float2 vp0, vp1, vp2, vp3;
    {
        const float* kp = kbase + (long)sr * HD_ + sc;
        kp0 = *(const float4*)kp; kp1 = *(const float4*)(kp + 32);
        const float* vp = vbase + (long)vr * HD_ + 2 * vc;
        vp0 = *(const float2*)vp;           vp1 = *(const float2*)(vp + HD_);
        vp2 = *(const float2*)(vp + 2*HD_); vp3 = *(const float2*)(vp + 3*HD_);
    }

    for (int kt = 0; kt < NKT; ++kt) {
        const int kb0 = kt * 32;
        __syncthreads();   // previous tile fully consumed
        {   // ---- write staged tile: RoPE K, repack V (b64 writes) ----
            const float pos = (float)(p0 + kb0 + sr);
            float ka[4] = {kp0.x,kp0.y,kp0.z,kp0.w};
            float kc[4] = {kp1.x,kp1.y,kp1.z,kp1.w};
            half4 o0, o1;
            #pragma unroll
            for (int i = 0; i < 4; ++i) {
                float sn, cs; __sincosf(pos * sinvk[i], &sn, &cs);
                o0[i] = (_Float16)(ka[i] * cs - kc[i] * sn);
                o1[i] = (_Float16)(kc[i] * cs + ka[i] * sn);
            }
            *(half4*)(&Kl[sr * KSTR + sc])      = o0;
            *(half4*)(&Kl[sr * KSTR + sc + 32]) = o1;
            half4 va, vb;
            va[0] = (_Float16)vp0.x; va[1] = (_Float16)vp1.x; va[2] = (_Float16)vp2.x; va[3] = (_Float16)vp3.x;
            vb[0] = (_Float16)vp0.y; vb[1] = (_Float16)vp1.y; vb[2] = (_Float16)vp2.y; vb[3] = (_Float16)vp3.y;
            *(half4*)(&Vt[(2 * vc)     * VSTR + vr]) = va;
            *(half4*)(&Vt[(2 * vc + 1) * VSTR + vr]) = vb;
        }
        if (kt + 1 < NKT) {   // ---- prefetch next tile (lands during compute) ----
            const int kb1 = kb0 + 32;
            const float* kp = kbase + (long)(kb1 + sr) * HD_ + sc;
            kp0 = *(const float4*)kp; kp1 = *(const float4*)(kp + 32);
            const float* vp = vbase + (long)(kb1 + vr) * HD_ + 2 * vc;
            vp0 = *(const float2*)vp;           vp1 = *(const float2*)(vp + HD_);
            vp2 = *(const float2*)(vp + 2*HD_); vp3 = *(const float2*)(vp + 3*HD_);
        }
        __syncthreads();   // tile visible

        // ---- fragments shared across strips ----
        half8 bk0[2], bk1[2], bv[4];
        #pragma unroll
        for (int ct = 0; ct < 2; ++ct) {
            const _Float16* kr = &Kl[(ct * 16 + ln) * KSTR + lg * 8];
            bk0[ct] = *(const half8*)kr;
            bk1[ct] = *(const half8*)(kr + 32);
        }
        #pragma unroll
        for (int dt = 0; dt < 4; ++dt)
            bv[dt] = *(const half8*)(&Vt[(dt * 16 + ln) * VSTR + lg * 8]);

        #pragma unroll
        for (int s = 0; s < 4; ++s) {
            if (kt >= nkt_s[s]) continue;          // wave-uniform
            const int qs = s * 256 + qoff;

            floatx4 sacc[2];
            #pragma unroll
            for (int ct = 0; ct < 2; ++ct) {
                floatx4 acc = (floatx4){0.f,0.f,0.f,0.f};
                acc = __builtin_amdgcn_mfma_f32_16x16x32_f16(aq[s][0], bk0[ct], acc, 0, 0, 0);
                acc = __builtin_amdgcn_mfma_f32_16x16x32_f16(aq[s][1], bk1[ct], acc, 0, 0, 0);
                sacc[ct] = acc;
            }
            if (kb0 + 31 > qs) {                   // diagonal tile: mask
                #pragma unroll
                for (int ct = 0; ct < 2; ++ct) {
                    const int kkc = kb0 + ct * 16 + ln;
                    #pragma unroll
                    for (int r = 0; r < 4; ++r)
                        if (kkc > qs + lg * 4 + r) sacc[ct][r] = -1e30f;
                }
            }

            // ---- deferred-max online softmax (log2 domain) ----
            float tm[4];
            int grow = 0;
            #pragma unroll
            for (int r = 0; r < 4; ++r) {
                tm[r] = rormax16(fmaxf(sacc[0][r], sacc[1][r]));
                grow |= (tm[r] > mr[s][r] + DTHR) ? 1 : 0;
            }
            if (__any(grow)) {                     // rare after the first tile of a strip
                #pragma unroll
                for (int r = 0; r < 4; ++r) {
                    float mnew  = fmaxf(mr[s][r], tm[r]);
                    float alpha = fast_exp2(mr[s][r] - mnew);
                    mr[s][r] = mnew;
                    Ol[s][r] *= alpha;
                    #pragma unroll
                    for (int dt = 0; dt < 4; ++dt) O[s][dt][r] *= alpha;
                }
            }

            // ---- P packed to f16 pairs, stored TRANSPOSED [k][q]: two b64 conflict-free writes ----
            uint2 wa, wb;
            wa.x = pk16(fast_exp2(sacc[0][0] - mr[s][0]), fast_exp2(sacc[0][1] - mr[s][1]));
            wa.y = pk16(fast_exp2(sacc[0][2] - mr[s][2]), fast_exp2(sacc[0][3] - mr[s][3]));
            wb.x = pk16(fast_exp2(sacc[1][0] - mr[s][0]), fast_exp2(sacc[1][1] - mr[s][1]));
            wb.y = pk16(fast_exp2(sacc[1][2] - mr[s][2]), fast_exp2(sacc[1][3] - mr[s][3]));
            *(uint2*)(&Pt[w][ ln       * 16 + lg * 4]) = wa;
            *(uint2*)(&Pt[w][(16 + ln) * 16 + lg * 4]) = wb;
            asm volatile("s_waitcnt lgkmcnt(0)" ::: "memory");
            // hardware transpose-read recovers the A-fragment: ap[j] = P[q=ln][k=8*lg+j]
            half4 tlo, thi;
            asm volatile("ds_read_b64_tr_b16 %0, %2\n\t"
                         "ds_read_b64_tr_b16 %1, %2 offset:128"
                         : "=&v"(tlo), "=&v"(thi) : "v"(trad));
            asm volatile("s_waitcnt lgkmcnt(0)" ::: "memory");
            __builtin_amdgcn_sched_barrier(0);
            half8 ap = __builtin_shufflevector(tlo, thi, 0, 1, 2, 3, 4, 5, 6, 7);

            #pragma unroll
            for (int dt = 0; dt < 4; ++dt)
                O[s][dt] = __builtin_amdgcn_mfma_f32_16x16x32_f16(ap, bv[dt], O[s][dt], 0, 0, 0);
            Ol[s] = __builtin_amdgcn_mfma_f32_16x16x32_f16(ap, bones, Ol[s], 0, 0, 0);
        }
    }

    // ---- epilogue ----
    #pragma unroll
    for (int s = 0; s < 4; ++s) {
        const int qs = s * 256 + qoff;
        float inv[4];
        #pragma unroll
        for (int r = 0; r < 4; ++r) inv[r] = 1.0f / Ol[s][r];
        #pragma unroll
        for (int dt = 0; dt < 4; ++dt) {
            #pragma unroll
            for (int r = 0; r < 4; ++r) {
                const int qr = qs + lg * 4 + r;
                outg[bhbase + (long)qr * HD_ + dt * 16 + ln] = O[s][dt][r] * inv[r];
            }
        }
    }
}

extern "C" void kernel_launch(void* const* d_in, const int* in_sizes, int n_in,
                              void* d_out, int out_size, void* d_ws, size_t ws_size,
                              hipStream_t stream) {
    const float* q    = (const float*)d_in[0];
    const float* k    = (const float*)d_in[1];
    const float* v    = (const float*)d_in[2];
    const int*   sidx = (const int*)d_in[3];
    float*       out  = (float*)d_out;

    dim3 grid(B_ * NC_ * H_ * 4);   // 1024 blocks: (j slow | b, n, h fast)
    dim3 block(256);
    attn_v5<<<grid, block, 0, stream>>>(q, k, v, sidx, out);
}